// Round 2
// baseline (113.219 us; speedup 1.0000x reference)
//
#include <hip/hip_runtime.h>

// ARLoss: loss = mean(max(0, |input - round(target)| - |input - z| + (pos ? 1e-6 : 0)))
//   pos = (input - round(target)) >= 0, z = pos ? ceil(input) : floor(input)
// Memory-bound streaming reduction over 2 x 8192 x 4096 fp32 inputs (268 MB).
// Single fused kernel: per-block partials + last-block-done final reduction
// (saves the ~4 us second launch that capped round 1 at 47.5 us).

#define EPSF 1e-6f

constexpr int THREADS = 256;
constexpr int MAX_BLOCKS = 2048;

__device__ __forceinline__ double block_reduce(double sum) {
#pragma unroll
    for (int off = 32; off > 0; off >>= 1)
        sum += __shfl_down(sum, off, 64);
    __shared__ double lds[THREADS / 64];
    const int lane = threadIdx.x & 63;
    const int wid  = threadIdx.x >> 6;
    if (lane == 0) lds[wid] = sum;
    __syncthreads();
    double s = 0.0;
    if (threadIdx.x == 0) {
#pragma unroll
        for (int w = 0; w < THREADS / 64; ++w) s += lds[w];
    }
    return s;  // valid in thread 0 only
}

__global__ __launch_bounds__(THREADS) void arloss_fused_kernel(
    const float4* __restrict__ x4, const float4* __restrict__ t4,
    float* __restrict__ out, unsigned* __restrict__ counter,
    double* __restrict__ partial, int n4, double inv_n) {
    double sum = 0.0;
    const int stride = gridDim.x * blockDim.x;
    for (int i = blockIdx.x * blockDim.x + threadIdx.x; i < n4; i += stride) {
        const float4 xv = x4[i];
        const float4 tv = t4[i];
        const float xs[4] = {xv.x, xv.y, xv.z, xv.w};
        const float ts[4] = {tv.x, tv.y, tv.z, tv.w};
#pragma unroll
        for (int j = 0; j < 4; ++j) {
            const float x = xs[j];
            const float c = rintf(ts[j]);          // round-half-to-even == jnp.round
            const float d = x - c;
            const bool pos = (d >= 0.0f);
            const float z = pos ? ceilf(x) : floorf(x);
            const float margin = fabsf(d) - fabsf(x - z) + (pos ? EPSF : 0.0f);
            sum += (double)fmaxf(0.0f, margin);
        }
    }

    const double bsum = block_reduce(sum);

    __shared__ bool is_last;
    if (threadIdx.x == 0) {
        partial[blockIdx.x] = bsum;            // one write per block, fixed slot
        __threadfence();                       // make partial visible device-wide
        const unsigned prev = atomicAdd(counter, 1u);   // device-scope
        is_last = (prev == gridDim.x - 1);
    }
    __syncthreads();

    if (is_last) {
        __threadfence();                       // acquire all partials
        double s = 0.0;
        for (int i = threadIdx.x; i < (int)gridDim.x; i += blockDim.x)
            s += partial[i];                   // fixed index order -> deterministic
        const double total = block_reduce(s);
        if (threadIdx.x == 0)
            out[0] = (float)(total * inv_n);
    }
}

extern "C" void kernel_launch(void* const* d_in, const int* in_sizes, int n_in,
                              void* d_out, int out_size, void* d_ws, size_t ws_size,
                              hipStream_t stream) {
    const float* input  = (const float*)d_in[0];
    const float* target = (const float*)d_in[1];
    float* out = (float*)d_out;

    const long long n = (long long)in_sizes[0];   // 33,554,432 (divisible by 4)
    const int n4 = (int)(n / 4);

    // workspace layout: [0..63] counter (only 4 bytes used, 64B-aligned pad),
    //                   [64 ..] per-block double partials
    unsigned* counter = (unsigned*)d_ws;
    double* partial = (double*)((char*)d_ws + 64);

    int blocks = MAX_BLOCKS;
    const int max_ws_blocks = (int)((ws_size - 64) / sizeof(double));
    if (blocks > max_ws_blocks) blocks = max_ws_blocks > 0 ? max_ws_blocks : 1;

    hipMemsetAsync(counter, 0, sizeof(unsigned), stream);  // capture-legal

    arloss_fused_kernel<<<blocks, THREADS, 0, stream>>>(
        (const float4*)input, (const float4*)target, out, counter,
        partial, n4, 1.0 / (double)n);
}

// Round 3
// 66.149 us; speedup vs baseline: 1.7116x; 1.7116x over previous
//
#include <hip/hip_runtime.h>

// ARLoss: loss = mean(max(0, |input - round(target)| - |input - z| + (pos ? 1e-6 : 0)))
//   pos = (input - round(target)) >= 0, z = pos ? ceil(input) : floor(input)
// Memory-bound streaming reduction over 2 x 8192 x 4096 fp32 inputs (268 MB).
//
// Round-2 lesson: agent-scope __threadfence() (L2 wb/inv across 8 XCDs) per
// block halved load BW. This version has NO fences: each block leader does a
// single fire-and-forget atomicAdd(float) of its pre-scaled partial into
// d_out[0] (device-scope by default on CDNA4, cheap — guide m20/G12).
// d_out zeroed via a 4-byte hipMemsetAsync node (capture-legal).

#define EPSF 1e-6f

constexpr int THREADS = 256;
constexpr int MAX_BLOCKS = 2048;

__global__ __launch_bounds__(THREADS) void arloss_kernel(
    const float4* __restrict__ x4, const float4* __restrict__ t4,
    float* __restrict__ out, int n4, double inv_n) {
    double sum = 0.0;
    const int stride = gridDim.x * blockDim.x;
    for (int i = blockIdx.x * blockDim.x + threadIdx.x; i < n4; i += stride) {
        const float4 xv = x4[i];
        const float4 tv = t4[i];
        const float xs[4] = {xv.x, xv.y, xv.z, xv.w};
        const float ts[4] = {tv.x, tv.y, tv.z, tv.w};
#pragma unroll
        for (int j = 0; j < 4; ++j) {
            const float x = xs[j];
            const float c = rintf(ts[j]);          // round-half-to-even == jnp.round
            const float d = x - c;
            const bool pos = (d >= 0.0f);
            const float z = pos ? ceilf(x) : floorf(x);
            const float margin = fabsf(d) - fabsf(x - z) + (pos ? EPSF : 0.0f);
            sum += (double)fmaxf(0.0f, margin);
        }
    }

    // wave (64-lane) reduction
#pragma unroll
    for (int off = 32; off > 0; off >>= 1)
        sum += __shfl_down(sum, off, 64);

    __shared__ double lds[THREADS / 64];
    const int lane = threadIdx.x & 63;
    const int wid  = threadIdx.x >> 6;
    if (lane == 0) lds[wid] = sum;
    __syncthreads();
    if (threadIdx.x == 0) {
        double s = 0.0;
#pragma unroll
        for (int w = 0; w < THREADS / 64; ++w) s += lds[w];
        // pre-scaled, fire-and-forget; no fence, no read-back
        atomicAdd(out, (float)(s * inv_n));
    }
}

extern "C" void kernel_launch(void* const* d_in, const int* in_sizes, int n_in,
                              void* d_out, int out_size, void* d_ws, size_t ws_size,
                              hipStream_t stream) {
    const float* input  = (const float*)d_in[0];
    const float* target = (const float*)d_in[1];
    float* out = (float*)d_out;

    const long long n = (long long)in_sizes[0];   // 33,554,432 (divisible by 4)
    const int n4 = (int)(n / 4);

    hipMemsetAsync(out, 0, sizeof(float), stream);  // capture-legal, 4 bytes

    arloss_kernel<<<MAX_BLOCKS, THREADS, 0, stream>>>(
        (const float4*)input, (const float4*)target, out, n4, 1.0 / (double)n);
}

// Round 4
// 49.365 us; speedup vs baseline: 2.2935x; 1.3400x over previous
//
#include <hip/hip_runtime.h>

// ARLoss: loss = mean(max(0, |input - round(target)| - |input - z| + (pos ? 1e-6 : 0)))
//   pos = (input - round(target)) >= 0, z = pos ? ceil(input) : floor(input)
// Memory-bound streaming reduction over 2 x 8192 x 4096 fp32 inputs (268 MB).
//
// Structure lock-in (empirical, rounds 1-3):
//   R1 two-kernel (partials in d_ws, no atomics/fences)      = 47.5 us  <- this
//   R3 fused, per-block same-address atomicAdd(float)        = 66.1 us
//   R2 fused, per-block __threadfence() (L2 wb/inv x 8 XCDs) = 113.2 us
// Effective read BW here = 268 MB / ~43.5 us main kernel = 6.17 TB/s
// (~98% of the 6.29 TB/s float4-copy ceiling; L3 serves ~half the stream).

#define EPSF 1e-6f

constexpr int THREADS = 256;
constexpr int MAX_BLOCKS = 2048;

__global__ __launch_bounds__(THREADS) void arloss_partial_kernel(
    const float4* __restrict__ x4, const float4* __restrict__ t4,
    double* __restrict__ partial, int n4) {
    double sum = 0.0;
    const int stride = gridDim.x * blockDim.x;
    for (int i = blockIdx.x * blockDim.x + threadIdx.x; i < n4; i += stride) {
        const float4 xv = x4[i];
        const float4 tv = t4[i];
        const float xs[4] = {xv.x, xv.y, xv.z, xv.w};
        const float ts[4] = {tv.x, tv.y, tv.z, tv.w};
#pragma unroll
        for (int j = 0; j < 4; ++j) {
            const float x = xs[j];
            const float c = rintf(ts[j]);          // round-half-to-even == jnp.round
            const float d = x - c;
            const bool pos = (d >= 0.0f);
            const float z = pos ? ceilf(x) : floorf(x);
            const float margin = fabsf(d) - fabsf(x - z) + (pos ? EPSF : 0.0f);
            sum += (double)fmaxf(0.0f, margin);
        }
    }
    // wave (64-lane) reduction
#pragma unroll
    for (int off = 32; off > 0; off >>= 1)
        sum += __shfl_down(sum, off, 64);
    __shared__ double lds[THREADS / 64];
    const int lane = threadIdx.x & 63;
    const int wid  = threadIdx.x >> 6;
    if (lane == 0) lds[wid] = sum;
    __syncthreads();
    if (threadIdx.x == 0) {
        double s = 0.0;
#pragma unroll
        for (int w = 0; w < THREADS / 64; ++w) s += lds[w];
        partial[blockIdx.x] = s;   // one deterministic write per block, no atomics
    }
}

__global__ __launch_bounds__(THREADS) void arloss_final_kernel(
    const double* __restrict__ partial, float* __restrict__ out,
    int nblocks, double inv_n) {
    double sum = 0.0;
    for (int i = threadIdx.x; i < nblocks; i += blockDim.x)
        sum += partial[i];
#pragma unroll
    for (int off = 32; off > 0; off >>= 1)
        sum += __shfl_down(sum, off, 64);
    __shared__ double lds[THREADS / 64];
    const int lane = threadIdx.x & 63;
    const int wid  = threadIdx.x >> 6;
    if (lane == 0) lds[wid] = sum;
    __syncthreads();
    if (threadIdx.x == 0) {
        double s = 0.0;
#pragma unroll
        for (int w = 0; w < THREADS / 64; ++w) s += lds[w];
        out[0] = (float)(s * inv_n);
    }
}

extern "C" void kernel_launch(void* const* d_in, const int* in_sizes, int n_in,
                              void* d_out, int out_size, void* d_ws, size_t ws_size,
                              hipStream_t stream) {
    const float* input  = (const float*)d_in[0];
    const float* target = (const float*)d_in[1];
    float* out = (float*)d_out;

    const long long n = (long long)in_sizes[0];   // 33,554,432 (divisible by 4)
    const int n4 = (int)(n / 4);

    int blocks = MAX_BLOCKS;
    const int max_ws_blocks = (int)(ws_size / sizeof(double));
    if (blocks > max_ws_blocks) blocks = max_ws_blocks > 0 ? max_ws_blocks : 1;

    double* partial = (double*)d_ws;

    arloss_partial_kernel<<<blocks, THREADS, 0, stream>>>(
        (const float4*)input, (const float4*)target, partial, n4);
    arloss_final_kernel<<<1, THREADS, 0, stream>>>(
        partial, out, blocks, 1.0 / (double)n);
}